// Round 12
// baseline (567.733 us; speedup 1.0000x reference)
//
#include <hip/hip_runtime.h>
#include <hip/hip_fp16.h>

#define NN 100000
#define EE 1600000
#define DD 32
#define CC 2
#define NLAYERS 4
#define GG 512
#define NHALF 50000                   // src slab boundary (3.2MB fp16 halves)

#define BSH 9                         // log2(nodes per dst-bucket)
#define BW 512                        // nodes per dst-bucket
#define NBUK ((NN + BW - 1) / BW)     // 196
#define CAP 12288                     // per-bucket staging capacity (mean 8163)
#define CH 2048                       // edges per partition block
#define NPART ((EE + CH - 1) / CH)    // 782

__device__ __forceinline__ float nt_load_half(const __half* p) {
    unsigned short u = __builtin_nontemporal_load(
        reinterpret_cast<const unsigned short*>(p));
    __half_raw hr; hr.x = u;
    return __half2float(__half(hr));
}
__device__ __forceinline__ void nt_store_half(float v, __half* p) {
    __half h = __float2half_rn(v);
    __half_raw hr = *reinterpret_cast<__half_raw*>(&h);
    __builtin_nontemporal_store(hr.x, reinterpret_cast<unsigned short*>(p));
}

// ---------------------------------------------------------------------------
// Phase 1: partition edges into NBUK dst-range buckets. LDS-staged so the
// global writes are coalesced runs. Packs (dst_local<<17 | src) into 4B.
// ---------------------------------------------------------------------------
__global__ void part_kernel(const int* __restrict__ ei,
                            int* __restrict__ gcur,
                            unsigned* __restrict__ part) {
    __shared__ unsigned sorted[CH];        // 8 KB
    __shared__ unsigned char sbkt[CH];     // 2 KB
    __shared__ int cnt[NBUK], offs[NBUK], cur[NBUK], gbs[NBUK];

    const int tid = threadIdx.x;
    const int eb  = blockIdx.x * CH;
    const int nch = min(CH, EE - eb);

    for (int b = tid; b < NBUK; b += 256) cnt[b] = 0;
    __syncthreads();
    for (int i = tid; i < nch; i += 256) {
        int dn = ei[EE + eb + i];
        atomicAdd(&cnt[dn >> BSH], 1);
    }
    __syncthreads();
    if (tid == 0) {
        int o = 0;
        for (int b = 0; b < NBUK; ++b) { offs[b] = o; o += cnt[b]; }
    }
    __syncthreads();
    if (tid < NBUK) {
        cur[tid] = offs[tid];
        gbs[tid] = cnt[tid] ? atomicAdd(&gcur[tid], cnt[tid]) : 0;
    }
    __syncthreads();
    for (int i = tid; i < nch; i += 256) {
        int s  = ei[eb + i];
        int dn = ei[EE + eb + i];
        int b  = dn >> BSH;
        unsigned pk = ((unsigned)(dn & (BW - 1)) << 17) | (unsigned)s;
        int p = atomicAdd(&cur[b], 1);
        sorted[p] = pk;
        sbkt[p]   = (unsigned char)b;
    }
    __syncthreads();
    for (int i = tid; i < nch; i += 256) {
        int b = sbkt[i];
        part[(size_t)b * CAP + gbs[b] + (i - offs[b])] = sorted[i];
    }
}

// Phase 2: exclusive scan of 196 bucket counts (trivial).
__global__ void bscan_kernel(const int* __restrict__ gcur,
                             int* __restrict__ bbase,
                             int* __restrict__ row_ptr) {
    if (threadIdx.x == 0 && blockIdx.x == 0) {
        int o = 0;
        for (int b = 0; b < NBUK; ++b) { bbase[b] = o; o += gcur[b]; }
        row_ptr[NN] = EE;
    }
}

// ---------------------------------------------------------------------------
// Phase 3: per-bucket local CSR. Additionally partitions each node's edges by
// src < NHALF (slab 0 first) and emits row_split = global boundary position.
// ---------------------------------------------------------------------------
__global__ void lcsr_kernel(const unsigned* __restrict__ part,
                            const int* __restrict__ gcur,
                            const int* __restrict__ bbase,
                            int* __restrict__ row_ptr,
                            int* __restrict__ row_split,
                            int* __restrict__ csr_src) {
    __shared__ int hcnt[BW];
    __shared__ int h0cnt[BW];
    __shared__ int a[2][BW];
    __shared__ int curA[BW];
    __shared__ int curB[BW];
    const int t    = threadIdx.x;
    const int b    = blockIdx.x;
    const int cntb = gcur[b];
    const int base = bbase[b];
    const size_t pb = (size_t)b * CAP;

    hcnt[t] = 0;
    h0cnt[t] = 0;
    __syncthreads();
    for (int i = t; i < cntb; i += BW) {
        unsigned pk = part[pb + i];
        int dl = pk >> 17;
        atomicAdd(&hcnt[dl], 1);
        if ((pk & 0x1FFFFu) < NHALF) atomicAdd(&h0cnt[dl], 1);
    }
    __syncthreads();
    int x = hcnt[t];
    a[0][t] = x;
    __syncthreads();
    int cb = 0;
    for (int off = 1; off < BW; off <<= 1) {
        int v = a[cb][t];
        if (t >= off) v += a[cb][t - off];
        a[cb ^ 1][t] = v;
        cb ^= 1;
        __syncthreads();
    }
    const int excl = a[cb][t] - x;
    const int node = b * BW + t;
    if (node < NN) {
        row_ptr[node]   = base + excl;
        row_split[node] = base + excl + h0cnt[t];
    }
    curA[t] = excl;                    // slab-0 slots
    curB[t] = excl + h0cnt[t];         // slab-1 slots
    __syncthreads();
    for (int i = t; i < cntb; i += BW) {
        unsigned pk = part[pb + i];
        int dl  = pk >> 17;
        int src = (int)(pk & 0x1FFFFu);
        int pos = base + ((src < NHALF) ? atomicAdd(&curA[dl], 1)
                                        : atomicAdd(&curB[dl], 1));
        csr_src[pos] = src;
    }
}

// ---------------------------------------------------------------------------
// Fused level-0 pool + f32->fp16 convert (single pass over node_emb).
// ---------------------------------------------------------------------------
__global__ void pool_cvt_kernel(const float* __restrict__ h,
                                const int* __restrict__ batch,
                                const float* __restrict__ Wd,
                                float* __restrict__ score,
                                __half* __restrict__ h16) {
    __shared__ float ss[GG * CC];
    __shared__ float sW[DD * CC];
    const int tid = threadIdx.x;
    for (int i = tid; i < GG * CC; i += 256) ss[i] = 0.f;
    if (tid < DD * CC) sW[tid] = Wd[tid];
    __syncthreads();

    const int d = tid & 31;
    const int grp = tid >> 5;
    const int n0 = blockIdx.x * 512;
    const int n1 = (n0 + 512 < NN) ? (n0 + 512) : NN;

    for (int n = n0 + grp; n < n1; n += 8) {
        float v = h[(size_t)n * DD + d];
        h16[(size_t)n * DD + d] = __float2half_rn(v);
        float p0 = v * sW[d * CC + 0];
        float p1 = v * sW[d * CC + 1];
        #pragma unroll
        for (int off = 16; off > 0; off >>= 1) {
            p0 += __shfl_xor(p0, off, 32);
            p1 += __shfl_xor(p1, off, 32);
        }
        if (d == 0) {
            int g = batch[n];
            atomicAdd(&ss[g * CC + 0], p0);
            atomicAdd(&ss[g * CC + 1], p1);
        }
    }
    __syncthreads();

    for (int i = tid; i < GG * CC; i += 256) {
        float v = ss[i];
        if (v != 0.f) atomicAdd(&score[i], v);
    }
}

// ---------------------------------------------------------------------------
// Gather macro ladder (r7-proven): register accumulator, 16/8/4/1 unroll.
// ---------------------------------------------------------------------------
#define GATHER_LADDER(acc, e, e1)                                             \
    for (; e + 16 <= e1; e += 16) {                                           \
        int ix[16];                                                           \
        _Pragma("unroll")                                                     \
        for (int i = 0; i < 16; ++i)                                          \
            ix[i] = __builtin_nontemporal_load(&csr_src[e + i]);              \
        __half v[16];                                                         \
        _Pragma("unroll")                                                     \
        for (int i = 0; i < 16; ++i) v[i] = h_in[(size_t)ix[i] * DD + d];     \
        float t0 = ((__half2float(v[0]) + __half2float(v[1])) +               \
                    (__half2float(v[2]) + __half2float(v[3]))) +              \
                   ((__half2float(v[4]) + __half2float(v[5])) +               \
                    (__half2float(v[6]) + __half2float(v[7])));               \
        float t1 = ((__half2float(v[8]) + __half2float(v[9])) +               \
                    (__half2float(v[10]) + __half2float(v[11]))) +            \
                   ((__half2float(v[12]) + __half2float(v[13])) +             \
                    (__half2float(v[14]) + __half2float(v[15])));             \
        acc += t0 + t1;                                                       \
    }                                                                         \
    if (e + 8 <= e1) {                                                        \
        int ix[8];                                                            \
        _Pragma("unroll")                                                     \
        for (int i = 0; i < 8; ++i)                                           \
            ix[i] = __builtin_nontemporal_load(&csr_src[e + i]);              \
        __half v[8];                                                          \
        _Pragma("unroll")                                                     \
        for (int i = 0; i < 8; ++i) v[i] = h_in[(size_t)ix[i] * DD + d];      \
        acc += ((__half2float(v[0]) + __half2float(v[1])) +                   \
                (__half2float(v[2]) + __half2float(v[3]))) +                  \
               ((__half2float(v[4]) + __half2float(v[5])) +                   \
                (__half2float(v[6]) + __half2float(v[7])));                   \
        e += 8;                                                               \
    }                                                                         \
    if (e + 4 <= e1) {                                                        \
        int ix[4];                                                            \
        _Pragma("unroll")                                                     \
        for (int i = 0; i < 4; ++i)                                           \
            ix[i] = __builtin_nontemporal_load(&csr_src[e + i]);              \
        __half v[4];                                                          \
        _Pragma("unroll")                                                     \
        for (int i = 0; i < 4; ++i) v[i] = h_in[(size_t)ix[i] * DD + d];      \
        acc += (__half2float(v[0]) + __half2float(v[1])) +                    \
               (__half2float(v[2]) + __half2float(v[3]));                     \
        e += 4;                                                               \
    }                                                                         \
    for (; e < e1; ++e)                                                       \
        acc += __half2float(h_in[(size_t)csr_src[e] * DD + d]);

// ---------------------------------------------------------------------------
// Layer pass 1: self term + gather of slab-0 srcs only (rows 0..NHALF =
// 3.2MB, fits the 4MB per-XCD L2 -> random reads become L2 hits, attacking
// the latency term of the per-CU outstanding-miss bound that r7-r10 showed
// to be invariant). agg written f32 coalesced, nontemporal.
// ---------------------------------------------------------------------------
__global__ __launch_bounds__(256) void gath0_kernel(
    const __half* __restrict__ h_in, float* __restrict__ agg,
    const int* __restrict__ row_ptr, const int* __restrict__ row_split,
    const int* __restrict__ csr_src) {
    const int tid = threadIdx.x;
    const int j = tid >> 5;
    const int d = tid & 31;
    const int base = blockIdx.x * 64;

    for (int s = 0; s < 8; ++s) {
        const int n = base + j * 8 + s;
        if (n >= NN) break;                 // uniform within the 32-lane group
        float acc = nt_load_half(&h_in[(size_t)n * DD + d]);  // self (stream)
        int e = row_ptr[n];
        const int e1 = row_split[n];
        GATHER_LADDER(acc, e, e1)
        __builtin_nontemporal_store(acc, &agg[(size_t)n * DD + d]);
    }
}

// ---------------------------------------------------------------------------
// Layer pass 2: acc from agg, gather slab-1 srcs (rows NHALF..NN, 3.2MB,
// L2-resident this pass), then proven MLP + fused pool.
// ---------------------------------------------------------------------------
__global__ __launch_bounds__(256) void layer_kernel(
    const __half* __restrict__ h_in, __half* __restrict__ h_out,
    const float* __restrict__ agg,
    const int* __restrict__ row_ptr, const int* __restrict__ row_split,
    const int* __restrict__ csr_src,
    const int* __restrict__ batch,
    const float* __restrict__ W1, const float* __restrict__ b1,
    const float* __restrict__ g1, const float* __restrict__ bt1,
    const float* __restrict__ W2, const float* __restrict__ b2,
    const float* __restrict__ g2, const float* __restrict__ bt2,
    const float* __restrict__ ng, const float* __restrict__ nb,
    const float* __restrict__ dWl, float* __restrict__ score) {
    __shared__ float sp[8 * DD];
    __shared__ float sdW[DD * CC];
    __shared__ float ss[GG * CC];      // 4 KB
    __shared__ float zA[64][DD];       // 8 KB
    __shared__ float z2loc[8][DD];     // 1 KB

    const int tid = threadIdx.x;
    const int j = tid >> 5;
    const int d = tid & 31;

    if (tid < DD) {
        sp[0 * DD + tid] = b1[tid];
        sp[1 * DD + tid] = g1[tid];
        sp[2 * DD + tid] = bt1[tid];
        sp[3 * DD + tid] = b2[tid];
        sp[4 * DD + tid] = g2[tid];
        sp[5 * DD + tid] = bt2[tid];
        sp[6 * DD + tid] = ng[tid];
        sp[7 * DD + tid] = nb[tid];
    }
    if (tid < DD * CC) sdW[tid] = dWl[tid];
    for (int i = tid; i < GG * CC; i += 256) ss[i] = 0.f;

    const float invs = 1.0f / sqrtf(1.001f);   // BN: mean=0, var=1, eps=1e-3
    const int base = blockIdx.x * 64;

    // phase 1: gather slab-1, starting from agg partial
    for (int s = 0; s < 8; ++s) {
        const int local = j * 8 + s;
        const int n = base + local;
        if (n >= NN) break;                 // uniform within the 32-lane group
        float acc = __builtin_nontemporal_load(&agg[(size_t)n * DD + d]);
        int e = row_split[n];
        const int e1 = row_ptr[n + 1];
        GATHER_LADDER(acc, e, e1)
        zA[local][d] = acc;
    }
    __syncthreads();

    // phase 2: MLP + fused pool (no barriers; z2loc stays within one wave)
    for (int s = 0; s < 8; ++s) {
        const int local = j * 8 + s;
        const int n = base + local;
        if (n >= NN) break;                 // uniform within the 32-lane group

        float a1 = sp[0 * DD + d];
        #pragma unroll
        for (int kk = 0; kk < DD; kk += 4) {
            const float4 zv = *reinterpret_cast<const float4*>(&zA[local][kk]);
            a1 += zv.x * W1[(kk + 0) * DD + d] + zv.y * W1[(kk + 1) * DD + d] +
                  zv.z * W1[(kk + 2) * DD + d] + zv.w * W1[(kk + 3) * DD + d];
        }
        float v = fmaxf(a1 * (sp[1 * DD + d] * invs) + sp[2 * DD + d], 0.f);
        z2loc[j][d] = v;                    // within-wave exchange (in-order LDS)

        float a2 = sp[3 * DD + d];
        #pragma unroll
        for (int kk = 0; kk < DD; kk += 4) {
            const float4 zv = *reinterpret_cast<const float4*>(&z2loc[j][kk]);
            a2 += zv.x * W2[(kk + 0) * DD + d] + zv.y * W2[(kk + 1) * DD + d] +
                  zv.z * W2[(kk + 2) * DD + d] + zv.w * W2[(kk + 3) * DD + d];
        }
        float w = fmaxf(a2 * (sp[4 * DD + d] * invs) + sp[5 * DD + d], 0.f);
        w = fmaxf(w * (sp[6 * DD + d] * invs) + sp[7 * DD + d], 0.f);
        nt_store_half(w, &h_out[(size_t)n * DD + d]);

        float p0 = w * sdW[d * CC + 0];
        float p1 = w * sdW[d * CC + 1];
        #pragma unroll
        for (int off = 16; off > 0; off >>= 1) {
            p0 += __shfl_xor(p0, off, 32);
            p1 += __shfl_xor(p1, off, 32);
        }
        if (d == 0) {
            int g = batch[n];
            atomicAdd(&ss[g * CC + 0], p0);
            atomicAdd(&ss[g * CC + 1], p1);
        }
    }
    __syncthreads();

    for (int i = tid; i < GG * CC; i += 256) {
        float v = ss[i];
        if (v != 0.f) atomicAdd(&score[i], v);
    }
}

__global__ void softmax_kernel(const float* __restrict__ score,
                               const float* __restrict__ db,
                               float* __restrict__ out) {
    int g = blockIdx.x * blockDim.x + threadIdx.x;
    if (g >= GG) return;
    float bs0 = 0.f, bs1 = 0.f;
    #pragma unroll
    for (int i = 0; i <= NLAYERS; ++i) {
        bs0 += db[i * CC + 0];
        bs1 += db[i * CC + 1];
    }
    float s0 = score[g * CC + 0] + bs0;
    float s1 = score[g * CC + 1] + bs1;
    float m = fmaxf(s0, s1);
    float e0 = expf(s0 - m), e1 = expf(s1 - m);
    float inv = 1.f / (e0 + e1);
    out[g * CC + 0] = e0 * inv;
    out[g * CC + 1] = e1 * inv;
}

extern "C" void kernel_launch(void* const* d_in, const int* in_sizes, int n_in,
                              void* d_out, int out_size, void* d_ws, size_t ws_size,
                              hipStream_t stream) {
    (void)in_sizes; (void)n_in; (void)out_size; (void)ws_size;

    const float* node_emb = (const float*)d_in[0];
    const int*   ei       = (const int*)d_in[1];
    const int*   batch    = (const int*)d_in[2];
    const float* W1       = (const float*)d_in[3];
    const float* b1       = (const float*)d_in[4];
    const float* g1       = (const float*)d_in[5];
    const float* bt1      = (const float*)d_in[6];
    const float* W2       = (const float*)d_in[7];
    const float* b2       = (const float*)d_in[8];
    const float* g2       = (const float*)d_in[9];
    const float* bt2      = (const float*)d_in[10];
    const float* ng       = (const float*)d_in[11];
    const float* nb       = (const float*)d_in[12];
    const float* dW       = (const float*)d_in[13];
    const float* db       = (const float*)d_in[14];
    float* out = (float*)d_out;

    // workspace layout (~40MB). part[] (9.6MB) aliases [hB16|hC16]: consumed
    // by lcsr before either is written.
    __half* hA16   = (__half*)d_ws;                   // [NN][DD] 6.4MB
    __half* hB16   = hA16 + (size_t)NN * DD;          // [NN][DD] 6.4MB
    __half* hC16   = hB16 + (size_t)NN * DD;          // [NN][DD] 6.4MB (cvt out)
    unsigned* part = (unsigned*)hB16;                 // [NBUK][CAP] alias
    float* score   = (float*)(hC16 + (size_t)NN * DD);// [GG][CC]
    int* row_ptr   = (int*)(score + GG * CC);         // [NN+1]
    int* csr_src   = row_ptr + NN + 2;                // [EE] 6.4MB (+pad)
    int* gcur      = csr_src + EE + 16;               // [256]
    int* bbase     = gcur + 256;                      // [256]
    int* row_split = bbase + 256;                     // [NN]
    float* agg     = (float*)(row_split + NN);        // [NN][DD] 12.8MB

    hipMemsetAsync(gcur, 0, 256 * sizeof(int), stream);
    hipMemsetAsync(score, 0, GG * CC * sizeof(float), stream);

    // CSR build (cache-local, slab-partitioned per node)
    part_kernel<<<NPART, 256, 0, stream>>>(ei, gcur, part);
    bscan_kernel<<<1, 64, 0, stream>>>(gcur, bbase, row_ptr);
    lcsr_kernel<<<NBUK, BW, 0, stream>>>(part, gcur, bbase, row_ptr,
                                         row_split, csr_src);

    // level-0 readout + fp16 working copy, single pass (after lcsr: alias)
    pool_cvt_kernel<<<(NN + 511) / 512, 256, 0, stream>>>(
        node_emb, batch, dW, score, hC16);

    const int layerGrid = (NN + 63) / 64;             // 1563
    const __half* cur_in = hC16;
    __half* bufs[2] = {hA16, hB16};
    for (int i = 0; i < NLAYERS; ++i) {
        __half* o = bufs[i & 1];
        gath0_kernel<<<layerGrid, 256, 0, stream>>>(
            cur_in, agg, row_ptr, row_split, csr_src);
        layer_kernel<<<layerGrid, 256, 0, stream>>>(
            cur_in, o, agg, row_ptr, row_split, csr_src, batch,
            W1 + (size_t)i * DD * DD, b1 + i * DD, g1 + i * DD, bt1 + i * DD,
            W2 + (size_t)i * DD * DD, b2 + i * DD, g2 + i * DD, bt2 + i * DD,
            ng + i * DD, nb + i * DD,
            dW + (size_t)(i + 1) * DD * CC, score);
        cur_in = o;
    }

    softmax_kernel<<<(GG + 255) / 256, 256, 0, stream>>>(score, db, out);
}

// Round 13
// 565.060 us; speedup vs baseline: 1.0047x; 1.0047x over previous
//
#include <hip/hip_runtime.h>
#include <hip/hip_fp16.h>

#define NN 100000
#define EE 1600000
#define DD 32
#define CC 2
#define NLAYERS 4
#define GG 512

#define BSH 9                         // log2(nodes per dst-bucket)
#define BW 512                        // nodes per dst-bucket
#define NBUK ((NN + BW - 1) / BW)     // 196
#define CAP 12288                     // per-bucket staging capacity (mean 8163)
#define CH 2048                       // edges per partition block
#define NPART ((EE + CH - 1) / CH)    // 782

// nontemporal fp16 helpers (nt policy -> no L1 allocation on gfx950)
__device__ __forceinline__ __half nt_load_h(const __half* p) {
    unsigned short u = __builtin_nontemporal_load(
        reinterpret_cast<const unsigned short*>(p));
    __half_raw hr; hr.x = u;
    return __half(hr);
}
__device__ __forceinline__ void nt_store_h(float v, __half* p) {
    __half h = __float2half_rn(v);
    __half_raw hr = *reinterpret_cast<__half_raw*>(&h);
    __builtin_nontemporal_store(hr.x, reinterpret_cast<unsigned short*>(p));
}

// ---------------------------------------------------------------------------
// Phase 1: partition edges into NBUK dst-range buckets. LDS-staged so the
// global writes are coalesced runs. Packs (dst_local<<17 | src) into 4B.
// ---------------------------------------------------------------------------
__global__ void part_kernel(const int* __restrict__ ei,
                            int* __restrict__ gcur,
                            unsigned* __restrict__ part) {
    __shared__ unsigned sorted[CH];        // 8 KB
    __shared__ unsigned char sbkt[CH];     // 2 KB
    __shared__ int cnt[NBUK], offs[NBUK], cur[NBUK], gbs[NBUK];

    const int tid = threadIdx.x;
    const int eb  = blockIdx.x * CH;
    const int nch = min(CH, EE - eb);

    for (int b = tid; b < NBUK; b += 256) cnt[b] = 0;
    __syncthreads();
    for (int i = tid; i < nch; i += 256) {
        int dn = ei[EE + eb + i];
        atomicAdd(&cnt[dn >> BSH], 1);
    }
    __syncthreads();
    if (tid == 0) {
        int o = 0;
        for (int b = 0; b < NBUK; ++b) { offs[b] = o; o += cnt[b]; }
    }
    __syncthreads();
    if (tid < NBUK) {
        cur[tid] = offs[tid];
        gbs[tid] = cnt[tid] ? atomicAdd(&gcur[tid], cnt[tid]) : 0;
    }
    __syncthreads();
    for (int i = tid; i < nch; i += 256) {
        int s  = ei[eb + i];
        int dn = ei[EE + eb + i];
        int b  = dn >> BSH;
        unsigned pk = ((unsigned)(dn & (BW - 1)) << 17) | (unsigned)s;
        int p = atomicAdd(&cur[b], 1);
        sorted[p] = pk;
        sbkt[p]   = (unsigned char)b;
    }
    __syncthreads();
    for (int i = tid; i < nch; i += 256) {
        int b = sbkt[i];
        part[(size_t)b * CAP + gbs[b] + (i - offs[b])] = sorted[i];
    }
}

// Phase 2: exclusive scan of 196 bucket counts (trivial).
__global__ void bscan_kernel(const int* __restrict__ gcur,
                             int* __restrict__ bbase,
                             int* __restrict__ row_ptr) {
    if (threadIdx.x == 0 && blockIdx.x == 0) {
        int o = 0;
        for (int b = 0; b < NBUK; ++b) { bbase[b] = o; o += gcur[b]; }
        row_ptr[NN] = EE;
    }
}

// ---------------------------------------------------------------------------
// Phase 3: per-bucket local CSR. Histogram + scan of 512 nodes in LDS; fill
// writes land in one contiguous ~32KB region -> L2-resident, no write amp.
// ---------------------------------------------------------------------------
__global__ void lcsr_kernel(const unsigned* __restrict__ part,
                            const int* __restrict__ gcur,
                            const int* __restrict__ bbase,
                            int* __restrict__ row_ptr,
                            int* __restrict__ csr_src) {
    __shared__ int hcnt[BW];
    __shared__ int a[2][BW];
    __shared__ int ccur[BW];
    const int t    = threadIdx.x;
    const int b    = blockIdx.x;
    const int cntb = gcur[b];
    const int base = bbase[b];
    const size_t pb = (size_t)b * CAP;

    hcnt[t] = 0;
    __syncthreads();
    for (int i = t; i < cntb; i += BW)
        atomicAdd(&hcnt[part[pb + i] >> 17], 1);
    __syncthreads();
    int x = hcnt[t];
    a[0][t] = x;
    __syncthreads();
    int cb = 0;
    for (int off = 1; off < BW; off <<= 1) {
        int v = a[cb][t];
        if (t >= off) v += a[cb][t - off];
        a[cb ^ 1][t] = v;
        cb ^= 1;
        __syncthreads();
    }
    const int excl = a[cb][t] - x;
    const int node = b * BW + t;
    if (node < NN) row_ptr[node] = base + excl;
    ccur[t] = excl;
    __syncthreads();
    for (int i = t; i < cntb; i += BW) {
        unsigned pk = part[pb + i];
        int dl  = pk >> 17;
        int pos = base + atomicAdd(&ccur[dl], 1);
        csr_src[pos] = (int)(pk & 0x1FFFFu);
    }
}

// ---------------------------------------------------------------------------
// Fused level-0 pool + f32->fp16 convert (single pass over node_emb).
// ---------------------------------------------------------------------------
__global__ void pool_cvt_kernel(const float* __restrict__ h,
                                const int* __restrict__ batch,
                                const float* __restrict__ Wd,
                                float* __restrict__ score,
                                __half* __restrict__ h16) {
    __shared__ float ss[GG * CC];
    __shared__ float sW[DD * CC];
    const int tid = threadIdx.x;
    for (int i = tid; i < GG * CC; i += 256) ss[i] = 0.f;
    if (tid < DD * CC) sW[tid] = Wd[tid];
    __syncthreads();

    const int d = tid & 31;
    const int grp = tid >> 5;
    const int n0 = blockIdx.x * 512;
    const int n1 = (n0 + 512 < NN) ? (n0 + 512) : NN;

    for (int n = n0 + grp; n < n1; n += 8) {
        float v = h[(size_t)n * DD + d];
        h16[(size_t)n * DD + d] = __float2half_rn(v);
        float p0 = v * sW[d * CC + 0];
        float p1 = v * sW[d * CC + 1];
        #pragma unroll
        for (int off = 16; off > 0; off >>= 1) {
            p0 += __shfl_xor(p0, off, 32);
            p1 += __shfl_xor(p1, off, 32);
        }
        if (d == 0) {
            int g = batch[n];
            atomicAdd(&ss[g * CC + 0], p0);
            atomicAdd(&ss[g * CC + 1], p1);
        }
    }
    __syncthreads();

    for (int i = tid; i < GG * CC; i += 256) {
        float v = ss[i];
        if (v != 0.f) atomicAdd(&score[i], v);
    }
}

// ---------------------------------------------------------------------------
// Fused GIN layer == r9 byte-for-byte EXCEPT: all h-row accesses (gather,
// self, h_out) are NONTEMPORAL -> `nt` policy, no L1 allocation. Isolated
// test of the L1-MSHR bottleneck theory: r7-r12 showed per-edge cost
// (~35 CU-cy) invariant to bytes, instruction count, waves, ILP, and
// L2-residency — the L1 miss path is the only stage common to all.
// ---------------------------------------------------------------------------
__global__ __launch_bounds__(256) void layer_kernel(
    const __half* __restrict__ h_in, __half* __restrict__ h_out,
    const int* __restrict__ row_ptr, const int* __restrict__ csr_src,
    const int* __restrict__ batch,
    const float* __restrict__ W1, const float* __restrict__ b1,
    const float* __restrict__ g1, const float* __restrict__ bt1,
    const float* __restrict__ W2, const float* __restrict__ b2,
    const float* __restrict__ g2, const float* __restrict__ bt2,
    const float* __restrict__ ng, const float* __restrict__ nb,
    const float* __restrict__ dWl, float* __restrict__ score) {
    __shared__ float sp[8 * DD];
    __shared__ float sdW[DD * CC];
    __shared__ float ss[GG * CC];      // 4 KB
    __shared__ float zA[64][DD];       // 8 KB
    __shared__ float z2loc[8][DD];     // 1 KB

    const int tid = threadIdx.x;
    const int j = tid >> 5;            // group 0..7
    const int d = tid & 31;

    if (tid < DD) {
        sp[0 * DD + tid] = b1[tid];
        sp[1 * DD + tid] = g1[tid];
        sp[2 * DD + tid] = bt1[tid];
        sp[3 * DD + tid] = b2[tid];
        sp[4 * DD + tid] = g2[tid];
        sp[5 * DD + tid] = bt2[tid];
        sp[6 * DD + tid] = ng[tid];
        sp[7 * DD + tid] = nb[tid];
    }
    if (tid < DD * CC) sdW[tid] = dWl[tid];
    for (int i = tid; i < GG * CC; i += 256) ss[i] = 0.f;

    const float invs = 1.0f / sqrtf(1.001f);   // BN: mean=0, var=1, eps=1e-3
    const int base = blockIdx.x * 64;

    // phase 1: per-node gather, register accumulator, 16/8/4/scalar ladder
    for (int s = 0; s < 8; ++s) {
        const int local = j * 8 + s;
        const int n = base + local;
        if (n >= NN) break;                 // uniform within the 32-lane group
        float acc = __half2float(nt_load_h(&h_in[(size_t)n * DD + d]));
        int e = row_ptr[n];
        const int e1 = row_ptr[n + 1];
        for (; e + 16 <= e1; e += 16) {
            int ix[16];
            #pragma unroll
            for (int i = 0; i < 16; ++i)
                ix[i] = __builtin_nontemporal_load(&csr_src[e + i]);
            __half v[16];
            #pragma unroll
            for (int i = 0; i < 16; ++i)
                v[i] = nt_load_h(&h_in[(size_t)ix[i] * DD + d]);
            float t0 = ((__half2float(v[0]) + __half2float(v[1])) +
                        (__half2float(v[2]) + __half2float(v[3]))) +
                       ((__half2float(v[4]) + __half2float(v[5])) +
                        (__half2float(v[6]) + __half2float(v[7])));
            float t1 = ((__half2float(v[8]) + __half2float(v[9])) +
                        (__half2float(v[10]) + __half2float(v[11]))) +
                       ((__half2float(v[12]) + __half2float(v[13])) +
                        (__half2float(v[14]) + __half2float(v[15])));
            acc += t0 + t1;
        }
        if (e + 8 <= e1) {
            int ix[8];
            #pragma unroll
            for (int i = 0; i < 8; ++i)
                ix[i] = __builtin_nontemporal_load(&csr_src[e + i]);
            __half v[8];
            #pragma unroll
            for (int i = 0; i < 8; ++i)
                v[i] = nt_load_h(&h_in[(size_t)ix[i] * DD + d]);
            acc += ((__half2float(v[0]) + __half2float(v[1])) +
                    (__half2float(v[2]) + __half2float(v[3]))) +
                   ((__half2float(v[4]) + __half2float(v[5])) +
                    (__half2float(v[6]) + __half2float(v[7])));
            e += 8;
        }
        if (e + 4 <= e1) {
            int ix[4];
            #pragma unroll
            for (int i = 0; i < 4; ++i)
                ix[i] = __builtin_nontemporal_load(&csr_src[e + i]);
            __half v[4];
            #pragma unroll
            for (int i = 0; i < 4; ++i)
                v[i] = nt_load_h(&h_in[(size_t)ix[i] * DD + d]);
            acc += (__half2float(v[0]) + __half2float(v[1])) +
                   (__half2float(v[2]) + __half2float(v[3]));
            e += 4;
        }
        for (; e < e1; ++e)
            acc += __half2float(nt_load_h(&h_in[(size_t)csr_src[e] * DD + d]));
        zA[local][d] = acc;
    }
    __syncthreads();

    // phase 2: MLP + fused pool (no barriers; z2loc stays within one wave)
    for (int s = 0; s < 8; ++s) {
        const int local = j * 8 + s;
        const int n = base + local;
        if (n >= NN) break;                 // uniform within the 32-lane group

        float a1 = sp[0 * DD + d];
        #pragma unroll
        for (int kk = 0; kk < DD; kk += 4) {
            const float4 zv = *reinterpret_cast<const float4*>(&zA[local][kk]);
            a1 += zv.x * W1[(kk + 0) * DD + d] + zv.y * W1[(kk + 1) * DD + d] +
                  zv.z * W1[(kk + 2) * DD + d] + zv.w * W1[(kk + 3) * DD + d];
        }
        float v = fmaxf(a1 * (sp[1 * DD + d] * invs) + sp[2 * DD + d], 0.f);
        z2loc[j][d] = v;                    // within-wave exchange (in-order LDS)

        float a2 = sp[3 * DD + d];
        #pragma unroll
        for (int kk = 0; kk < DD; kk += 4) {
            const float4 zv = *reinterpret_cast<const float4*>(&z2loc[j][kk]);
            a2 += zv.x * W2[(kk + 0) * DD + d] + zv.y * W2[(kk + 1) * DD + d] +
                  zv.z * W2[(kk + 2) * DD + d] + zv.w * W2[(kk + 3) * DD + d];
        }
        float w = fmaxf(a2 * (sp[4 * DD + d] * invs) + sp[5 * DD + d], 0.f);
        w = fmaxf(w * (sp[6 * DD + d] * invs) + sp[7 * DD + d], 0.f);
        nt_store_h(w, &h_out[(size_t)n * DD + d]);

        float p0 = w * sdW[d * CC + 0];
        float p1 = w * sdW[d * CC + 1];
        #pragma unroll
        for (int off = 16; off > 0; off >>= 1) {
            p0 += __shfl_xor(p0, off, 32);
            p1 += __shfl_xor(p1, off, 32);
        }
        if (d == 0) {
            int g = batch[n];
            atomicAdd(&ss[g * CC + 0], p0);
            atomicAdd(&ss[g * CC + 1], p1);
        }
    }
    __syncthreads();

    for (int i = tid; i < GG * CC; i += 256) {
        float v = ss[i];
        if (v != 0.f) atomicAdd(&score[i], v);
    }
}

__global__ void softmax_kernel(const float* __restrict__ score,
                               const float* __restrict__ db,
                               float* __restrict__ out) {
    int g = blockIdx.x * blockDim.x + threadIdx.x;
    if (g >= GG) return;
    float bs0 = 0.f, bs1 = 0.f;
    #pragma unroll
    for (int i = 0; i <= NLAYERS; ++i) {
        bs0 += db[i * CC + 0];
        bs1 += db[i * CC + 1];
    }
    float s0 = score[g * CC + 0] + bs0;
    float s1 = score[g * CC + 1] + bs1;
    float m = fmaxf(s0, s1);
    float e0 = expf(s0 - m), e1 = expf(s1 - m);
    float inv = 1.f / (e0 + e1);
    out[g * CC + 0] = e0 * inv;
    out[g * CC + 1] = e1 * inv;
}

extern "C" void kernel_launch(void* const* d_in, const int* in_sizes, int n_in,
                              void* d_out, int out_size, void* d_ws, size_t ws_size,
                              hipStream_t stream) {
    (void)in_sizes; (void)n_in; (void)out_size; (void)ws_size;

    const float* node_emb = (const float*)d_in[0];
    const int*   ei       = (const int*)d_in[1];
    const int*   batch    = (const int*)d_in[2];
    const float* W1       = (const float*)d_in[3];
    const float* b1       = (const float*)d_in[4];
    const float* g1       = (const float*)d_in[5];
    const float* bt1      = (const float*)d_in[6];
    const float* W2       = (const float*)d_in[7];
    const float* b2       = (const float*)d_in[8];
    const float* g2       = (const float*)d_in[9];
    const float* bt2      = (const float*)d_in[10];
    const float* ng       = (const float*)d_in[11];
    const float* nb       = (const float*)d_in[12];
    const float* dW       = (const float*)d_in[13];
    const float* db       = (const float*)d_in[14];
    float* out = (float*)d_out;

    // workspace layout. part[] (9.6MB) aliases [hB16|hC16]: consumed by lcsr
    // before pool_cvt writes hC16 / layer 1 writes hB16.
    __half* hA16   = (__half*)d_ws;                   // [NN][DD] 6.4MB
    __half* hB16   = hA16 + (size_t)NN * DD;          // [NN][DD] 6.4MB
    __half* hC16   = hB16 + (size_t)NN * DD;          // [NN][DD] 6.4MB (cvt out)
    unsigned* part = (unsigned*)hB16;                 // [NBUK][CAP] alias
    float* score   = (float*)(hC16 + (size_t)NN * DD);// [GG][CC]
    int* row_ptr   = (int*)(score + GG * CC);         // [NN+1]
    int* csr_src   = row_ptr + NN + 2;                // [EE] 6.4MB (+pad)
    int* gcur      = csr_src + EE + 16;               // [256]
    int* bbase     = gcur + 256;                      // [256]

    hipMemsetAsync(gcur, 0, 256 * sizeof(int), stream);
    hipMemsetAsync(score, 0, GG * CC * sizeof(float), stream);

    // CSR build (cache-local)
    part_kernel<<<NPART, 256, 0, stream>>>(ei, gcur, part);
    bscan_kernel<<<1, 64, 0, stream>>>(gcur, bbase, row_ptr);
    lcsr_kernel<<<NBUK, BW, 0, stream>>>(part, gcur, bbase, row_ptr, csr_src);

    // level-0 readout + fp16 working copy, single pass (after lcsr: alias)
    pool_cvt_kernel<<<(NN + 511) / 512, 256, 0, stream>>>(
        node_emb, batch, dW, score, hC16);

    const int layerGrid = (NN + 63) / 64;             // 1563
    const __half* cur_in = hC16;
    __half* bufs[2] = {hA16, hB16};
    for (int i = 0; i < NLAYERS; ++i) {
        __half* o = bufs[i & 1];
        layer_kernel<<<layerGrid, 256, 0, stream>>>(
            cur_in, o, row_ptr, csr_src, batch,
            W1 + (size_t)i * DD * DD, b1 + i * DD, g1 + i * DD, bt1 + i * DD,
            W2 + (size_t)i * DD * DD, b2 + i * DD, g2 + i * DD, bt2 + i * DD,
            ng + i * DD, nb + i * DD,
            dW + (size_t)(i + 1) * DD * CC, score);
        cur_in = o;
    }

    softmax_kernel<<<(GG + 255) / 256, 256, 0, stream>>>(score, db, out);
}

// Round 14
// 442.841 us; speedup vs baseline: 1.2820x; 1.2760x over previous
//
#include <hip/hip_runtime.h>

#define NN 100000
#define EE 1600000
#define DD 32
#define CC 2
#define NLAYERS 4
#define GG 512

#define BSH 9                         // log2(nodes per dst-bucket)
#define BW 512                        // nodes per dst-bucket
#define NBUK ((NN + BW - 1) / BW)     // 196
#define CAP 12288                     // per-bucket staging capacity (mean 8163)
#define CH 2048                       // edges per partition block
#define NPART ((EE + CH - 1) / CH)    // 782

// ---------------------------------------------------------------------------
// Phase 1: partition edges into NBUK dst-range buckets. LDS-staged so the
// global writes are coalesced runs. Packs (dst_local<<17 | src) into 4B.
// ---------------------------------------------------------------------------
__global__ void part_kernel(const int* __restrict__ ei,
                            int* __restrict__ gcur,
                            unsigned* __restrict__ part) {
    __shared__ unsigned sorted[CH];        // 8 KB
    __shared__ unsigned char sbkt[CH];     // 2 KB
    __shared__ int cnt[NBUK], offs[NBUK], cur[NBUK], gbs[NBUK];

    const int tid = threadIdx.x;
    const int eb  = blockIdx.x * CH;
    const int nch = min(CH, EE - eb);

    for (int b = tid; b < NBUK; b += 256) cnt[b] = 0;
    __syncthreads();
    for (int i = tid; i < nch; i += 256) {
        int dn = ei[EE + eb + i];
        atomicAdd(&cnt[dn >> BSH], 1);
    }
    __syncthreads();
    if (tid == 0) {
        int o = 0;
        for (int b = 0; b < NBUK; ++b) { offs[b] = o; o += cnt[b]; }
    }
    __syncthreads();
    if (tid < NBUK) {
        cur[tid] = offs[tid];
        gbs[tid] = cnt[tid] ? atomicAdd(&gcur[tid], cnt[tid]) : 0;
    }
    __syncthreads();
    for (int i = tid; i < nch; i += 256) {
        int s  = ei[eb + i];
        int dn = ei[EE + eb + i];
        int b  = dn >> BSH;
        unsigned pk = ((unsigned)(dn & (BW - 1)) << 17) | (unsigned)s;
        int p = atomicAdd(&cur[b], 1);
        sorted[p] = pk;
        sbkt[p]   = (unsigned char)b;
    }
    __syncthreads();
    for (int i = tid; i < nch; i += 256) {
        int b = sbkt[i];
        part[(size_t)b * CAP + gbs[b] + (i - offs[b])] = sorted[i];
    }
}

// Phase 2: exclusive scan of 196 bucket counts (trivial).
__global__ void bscan_kernel(const int* __restrict__ gcur,
                             int* __restrict__ bbase,
                             int* __restrict__ row_ptr) {
    if (threadIdx.x == 0 && blockIdx.x == 0) {
        int o = 0;
        for (int b = 0; b < NBUK; ++b) { bbase[b] = o; o += gcur[b]; }
        row_ptr[NN] = EE;
    }
}

// ---------------------------------------------------------------------------
// Phase 3: per-bucket local CSR. Histogram + scan of 512 nodes in LDS; fill
// writes land in one contiguous ~32KB region -> L2-resident, no write amp.
// ---------------------------------------------------------------------------
__global__ void lcsr_kernel(const unsigned* __restrict__ part,
                            const int* __restrict__ gcur,
                            const int* __restrict__ bbase,
                            int* __restrict__ row_ptr,
                            unsigned* __restrict__ csr_packed) {
    __shared__ int hcnt[BW];
    __shared__ int a[2][BW];
    __shared__ int ccur[BW];
    const int t    = threadIdx.x;
    const int b    = blockIdx.x;
    const int cntb = gcur[b];
    const int base = bbase[b];
    const size_t pb = (size_t)b * CAP;

    hcnt[t] = 0;
    __syncthreads();
    for (int i = t; i < cntb; i += BW)
        atomicAdd(&hcnt[part[pb + i] >> 17], 1);
    __syncthreads();
    int x = hcnt[t];
    a[0][t] = x;
    __syncthreads();
    int cb = 0;
    for (int off = 1; off < BW; off <<= 1) {
        int v = a[cb][t];
        if (t >= off) v += a[cb][t - off];
        a[cb ^ 1][t] = v;
        cb ^= 1;
        __syncthreads();
    }
    const int excl = a[cb][t] - x;
    const int node = b * BW + t;
    if (node < NN) row_ptr[node] = base + excl;
    ccur[t] = excl;
    __syncthreads();
    for (int i = t; i < cntb; i += BW) {
        unsigned pk = part[pb + i];
        int dl  = pk >> 17;
        int pos = base + atomicAdd(&ccur[dl], 1);
        csr_packed[pos] = ((unsigned)(dl & 63) << 17) | (pk & 0x1FFFFu);
    }
}

// ---------------------------------------------------------------------------
// Fused GIN layer (r7 = best measured config, restored). Block = 64 nodes,
// 8 groups x 8 nodes. Phase 1: per-node gather with REGISTER accumulator and
// a 16/8/4/scalar unroll ladder (16 independent h-row loads in flight per
// group). ONE barrier. Phase 2: barrier-free MLP (W via global/L1, z
// broadcast from LDS, z2 exchange within-wave) + fused pooled readout into
// LDS score image. Post-mortem of r8-r13: every alternative (more waves,
// fewer VMEM instrs, fp16, L2-resident slabs, L1 bypass) regressed —
// per-edge cost ~35 CU-cy is the chip's random-gather service rate.
// ---------------------------------------------------------------------------
__global__ __launch_bounds__(256) void layer_kernel(
    const float* __restrict__ h_in, float* __restrict__ h_out,
    const int* __restrict__ row_ptr, const unsigned* __restrict__ csr_packed,
    const int* __restrict__ batch,
    const float* __restrict__ W1, const float* __restrict__ b1,
    const float* __restrict__ g1, const float* __restrict__ bt1,
    const float* __restrict__ W2, const float* __restrict__ b2,
    const float* __restrict__ g2, const float* __restrict__ bt2,
    const float* __restrict__ ng, const float* __restrict__ nb,
    const float* __restrict__ dWl, float* __restrict__ score) {
    __shared__ float sp[8 * DD];
    __shared__ float sdW[DD * CC];
    __shared__ float ss[GG * CC];      // 4 KB
    __shared__ float zA[64][DD];       // 8 KB
    __shared__ float z2loc[8][DD];     // 1 KB

    const int tid = threadIdx.x;
    const int j = tid >> 5;            // group 0..7
    const int d = tid & 31;

    if (tid < DD) {
        sp[0 * DD + tid] = b1[tid];
        sp[1 * DD + tid] = g1[tid];
        sp[2 * DD + tid] = bt1[tid];
        sp[3 * DD + tid] = b2[tid];
        sp[4 * DD + tid] = g2[tid];
        sp[5 * DD + tid] = bt2[tid];
        sp[6 * DD + tid] = ng[tid];
        sp[7 * DD + tid] = nb[tid];
    }
    if (tid < DD * CC) sdW[tid] = dWl[tid];
    for (int i = tid; i < GG * CC; i += 256) ss[i] = 0.f;

    const float invs = 1.0f / sqrtf(1.001f);   // BN: mean=0, var=1, eps=1e-3
    const int base = blockIdx.x * 64;

    // phase 1: per-node gather, deep unroll ladder (16 loads in flight)
    for (int s = 0; s < 8; ++s) {
        const int local = j * 8 + s;
        const int n = base + local;
        if (n >= NN) break;                 // uniform within the 32-lane group
        float acc = h_in[(size_t)n * DD + d];
        int e = row_ptr[n];
        const int e1 = row_ptr[n + 1];
        for (; e + 16 <= e1; e += 16) {
            unsigned ix[16];
            #pragma unroll
            for (int i = 0; i < 16; ++i) ix[i] = csr_packed[e + i] & 0x1FFFFu;
            float v[16];
            #pragma unroll
            for (int i = 0; i < 16; ++i) v[i] = h_in[(size_t)ix[i] * DD + d];
            float t0 = ((v[0] + v[1]) + (v[2] + v[3])) +
                       ((v[4] + v[5]) + (v[6] + v[7]));
            float t1 = ((v[8] + v[9]) + (v[10] + v[11])) +
                       ((v[12] + v[13]) + (v[14] + v[15]));
            acc += t0 + t1;
        }
        if (e + 8 <= e1) {
            unsigned ix[8];
            #pragma unroll
            for (int i = 0; i < 8; ++i) ix[i] = csr_packed[e + i] & 0x1FFFFu;
            float v[8];
            #pragma unroll
            for (int i = 0; i < 8; ++i) v[i] = h_in[(size_t)ix[i] * DD + d];
            acc += ((v[0] + v[1]) + (v[2] + v[3])) +
                   ((v[4] + v[5]) + (v[6] + v[7]));
            e += 8;
        }
        if (e + 4 <= e1) {
            unsigned ix[4];
            #pragma unroll
            for (int i = 0; i < 4; ++i) ix[i] = csr_packed[e + i] & 0x1FFFFu;
            float v[4];
            #pragma unroll
            for (int i = 0; i < 4; ++i) v[i] = h_in[(size_t)ix[i] * DD + d];
            acc += (v[0] + v[1]) + (v[2] + v[3]);
            e += 4;
        }
        for (; e < e1; ++e)
            acc += h_in[(size_t)(csr_packed[e] & 0x1FFFFu) * DD + d];
        zA[local][d] = acc;
    }
    __syncthreads();

    // phase 2: MLP + fused pool (no barriers; z2loc stays within one wave)
    for (int s = 0; s < 8; ++s) {
        const int local = j * 8 + s;
        const int n = base + local;
        if (n >= NN) break;                 // uniform within the 32-lane group

        float a1 = sp[0 * DD + d];
        #pragma unroll
        for (int kk = 0; kk < DD; kk += 4) {
            const float4 zv = *reinterpret_cast<const float4*>(&zA[local][kk]);
            a1 += zv.x * W1[(kk + 0) * DD + d] + zv.y * W1[(kk + 1) * DD + d] +
                  zv.z * W1[(kk + 2) * DD + d] + zv.w * W1[(kk + 3) * DD + d];
        }
        float v = fmaxf(a1 * (sp[1 * DD + d] * invs) + sp[2 * DD + d], 0.f);
        z2loc[j][d] = v;                    // within-wave exchange (in-order LDS)

        float a2 = sp[3 * DD + d];
        #pragma unroll
        for (int kk = 0; kk < DD; kk += 4) {
            const float4 zv = *reinterpret_cast<const float4*>(&z2loc[j][kk]);
            a2 += zv.x * W2[(kk + 0) * DD + d] + zv.y * W2[(kk + 1) * DD + d] +
                  zv.z * W2[(kk + 2) * DD + d] + zv.w * W2[(kk + 3) * DD + d];
        }
        float w = fmaxf(a2 * (sp[4 * DD + d] * invs) + sp[5 * DD + d], 0.f);
        w = fmaxf(w * (sp[6 * DD + d] * invs) + sp[7 * DD + d], 0.f);
        h_out[(size_t)n * DD + d] = w;

        float p0 = w * sdW[d * CC + 0];
        float p1 = w * sdW[d * CC + 1];
        #pragma unroll
        for (int off = 16; off > 0; off >>= 1) {
            p0 += __shfl_xor(p0, off, 32);
            p1 += __shfl_xor(p1, off, 32);
        }
        if (d == 0) {
            int g = batch[n];
            atomicAdd(&ss[g * CC + 0], p0);
            atomicAdd(&ss[g * CC + 1], p1);
        }
    }
    __syncthreads();

    for (int i = tid; i < GG * CC; i += 256) {
        float v = ss[i];
        if (v != 0.f) atomicAdd(&score[i], v);
    }
}

// ---------------------------------------------------------------------------
// Pool + readout for hidden level 0 (raw embeddings)
// ---------------------------------------------------------------------------
__global__ void pool_kernel(const float* __restrict__ h,
                            const int* __restrict__ batch,
                            const float* __restrict__ Wd,
                            float* __restrict__ score) {
    __shared__ float ss[GG * CC];
    __shared__ float sW[DD * CC];
    const int tid = threadIdx.x;
    for (int i = tid; i < GG * CC; i += 256) ss[i] = 0.f;
    if (tid < DD * CC) sW[tid] = Wd[tid];
    __syncthreads();

    const int d = tid & 31;
    const int grp = tid >> 5;
    const int n0 = blockIdx.x * 512;
    const int n1 = (n0 + 512 < NN) ? (n0 + 512) : NN;

    for (int n = n0 + grp; n < n1; n += 8) {
        float v = h[(size_t)n * DD + d];
        float p0 = v * sW[d * CC + 0];
        float p1 = v * sW[d * CC + 1];
        #pragma unroll
        for (int off = 16; off > 0; off >>= 1) {
            p0 += __shfl_xor(p0, off, 32);
            p1 += __shfl_xor(p1, off, 32);
        }
        if (d == 0) {
            int g = batch[n];
            atomicAdd(&ss[g * CC + 0], p0);
            atomicAdd(&ss[g * CC + 1], p1);
        }
    }
    __syncthreads();

    for (int i = tid; i < GG * CC; i += 256) {
        float v = ss[i];
        if (v != 0.f) atomicAdd(&score[i], v);
    }
}

__global__ void softmax_kernel(const float* __restrict__ score,
                               const float* __restrict__ db,
                               float* __restrict__ out) {
    int g = blockIdx.x * blockDim.x + threadIdx.x;
    if (g >= GG) return;
    float bs0 = 0.f, bs1 = 0.f;
    #pragma unroll
    for (int i = 0; i <= NLAYERS; ++i) {
        bs0 += db[i * CC + 0];
        bs1 += db[i * CC + 1];
    }
    float s0 = score[g * CC + 0] + bs0;
    float s1 = score[g * CC + 1] + bs1;
    float m = fmaxf(s0, s1);
    float e0 = expf(s0 - m), e1 = expf(s1 - m);
    float inv = 1.f / (e0 + e1);
    out[g * CC + 0] = e0 * inv;
    out[g * CC + 1] = e1 * inv;
}

extern "C" void kernel_launch(void* const* d_in, const int* in_sizes, int n_in,
                              void* d_out, int out_size, void* d_ws, size_t ws_size,
                              hipStream_t stream) {
    (void)in_sizes; (void)n_in; (void)out_size; (void)ws_size;

    const float* node_emb = (const float*)d_in[0];
    const int*   ei       = (const int*)d_in[1];
    const int*   batch    = (const int*)d_in[2];
    const float* W1       = (const float*)d_in[3];
    const float* b1       = (const float*)d_in[4];
    const float* g1       = (const float*)d_in[5];
    const float* bt1      = (const float*)d_in[6];
    const float* W2       = (const float*)d_in[7];
    const float* b2       = (const float*)d_in[8];
    const float* g2       = (const float*)d_in[9];
    const float* bt2      = (const float*)d_in[10];
    const float* ng       = (const float*)d_in[11];
    const float* nb       = (const float*)d_in[12];
    const float* dW       = (const float*)d_in[13];
    const float* db       = (const float*)d_in[14];
    float* out = (float*)d_out;

    // workspace layout (part[] aliases hB: hB is first written by layer 2,
    // long after lcsr has consumed part[])
    float* hA      = (float*)d_ws;                    // [NN][DD] 12.8MB
    float* hB      = hA + (size_t)NN * DD;            // [NN][DD] 12.8MB
    unsigned* part = (unsigned*)hB;                   // [NBUK][CAP] 9.6MB alias
    float* score   = hB + (size_t)NN * DD;            // [GG][CC]
    int* row_ptr   = (int*)(score + GG * CC);         // [NN+1]
    unsigned* csr_packed = (unsigned*)(row_ptr + NN + 2);  // [EE] 6.4MB
    int* gcur      = (int*)(csr_packed + EE);         // [256]
    int* bbase     = gcur + 256;                      // [256]

    hipMemsetAsync(gcur, 0, 256 * sizeof(int), stream);
    hipMemsetAsync(score, 0, GG * CC * sizeof(float), stream);

    // CSR build (cache-local)
    part_kernel<<<NPART, 256, 0, stream>>>(ei, gcur, part);
    bscan_kernel<<<1, 64, 0, stream>>>(gcur, bbase, row_ptr);
    lcsr_kernel<<<NBUK, BW, 0, stream>>>(part, gcur, bbase, row_ptr, csr_packed);

    // hidden level 0 readout on raw embeddings
    pool_kernel<<<(NN + 511) / 512, 256, 0, stream>>>(node_emb, batch, dW, score);

    const int layerGrid = (NN + 63) / 64;             // 1563
    const float* cur_in = node_emb;
    float* bufs[2] = {hA, hB};
    for (int i = 0; i < NLAYERS; ++i) {
        float* o = bufs[i & 1];
        layer_kernel<<<layerGrid, 256, 0, stream>>>(
            cur_in, o, row_ptr, csr_packed, batch,
            W1 + (size_t)i * DD * DD, b1 + i * DD, g1 + i * DD, bt1 + i * DD,
            W2 + (size_t)i * DD * DD, b2 + i * DD, g2 + i * DD, bt2 + i * DD,
            ng + i * DD, nb + i * DD,
            dW + (size_t)(i + 1) * DD * CC, score);
        cur_in = o;
    }

    softmax_kernel<<<(GG + 255) / 256, 256, 0, stream>>>(score, db, out);
}